// Round 1
// baseline (1197.466 us; speedup 1.0000x reference)
//
#include <hip/hip_runtime.h>

// x:   (2,4,8,8,8,96,96) fp32   strides: b 18874368, ci 4718592, cd 589824, t 73728, d 9216, h 96, w 1
// W:   (9,4,4,3,3,3)     fp32   strides: ij 432, o 108, ci 27, kd 9, kh 3, kw 1
// b:   (9,4)             fp32
// out: (2,4,6,6,8,96,96) fp32   strides: b 10616832, o 2654208, c 442368, t 73728, d 9216, h 96, w 1

#define BLOCK 256

__global__ __launch_bounds__(256) void conv5d_kernel(
    const float* __restrict__ xg,
    const float* __restrict__ Wg,
    const float* __restrict__ bg,
    float* __restrict__ outg)
{
    // Stage weights into LDS, transposed so the 4 'o' values are contiguous:
    // wl layout: [ci][ij][kd][kh][kw][o]
    __shared__ float wl[3888];
    for (int k = threadIdx.x; k < 3888; k += BLOCK) {
        int o  = k & 3;  int r = k >> 2;
        int kw = r % 3;  r /= 3;
        int kh = r % 3;  r /= 3;
        int kd = r % 3;  r /= 3;
        int ij = r % 9;  int ci = r / 9;
        wl[k] = Wg[ij*432 + o*108 + ci*27 + kd*9 + kh*3 + kw];
    }
    __syncthreads();

    int gid = blockIdx.x * BLOCK + threadIdx.x;   // exact: 663552 threads, 2592 blocks
    int wv  = gid % 12;  int tmp = gid / 12;
    int h   = tmp % 96;  tmp /= 96;
    int d   = tmp % 8;   tmp /= 8;
    int t   = tmp % 6;   tmp /= 6;
    int c   = tmp % 6;   tmp /= 6;
    int b   = tmp;       // 0..1
    int w0  = wv * 8;

    const float* xb = xg + (size_t)b * 18874368;

    float acc[4][8];
    #pragma unroll
    for (int o = 0; o < 4; ++o)
        #pragma unroll
        for (int v = 0; v < 8; ++v) acc[o][v] = 0.f;

    for (int ci = 0; ci < 4; ++ci) {
        for (int i = 0; i < 3; ++i) {
            for (int j = 0; j < 3; ++j) {
                const float* xp  = xb + (size_t)ci*4718592
                                      + (size_t)(c + i)*589824
                                      + (size_t)(t + j)*73728;
                const float* wlp = &wl[(ci*9 + i*3 + j) * 27 * 4];
                #pragma unroll
                for (int kd = 0; kd < 3; ++kd) {
                    int dd = d + kd - 1;
                    if ((unsigned)dd >= 8u) continue;
                    #pragma unroll
                    for (int kh = 0; kh < 3; ++kh) {
                        int hh = h + kh - 1;
                        if ((unsigned)hh >= 96u) continue;
                        const float* xr = xp + dd*9216 + hh*96 + w0;
                        float xv[10];
                        xv[0] = (w0 > 0) ? xr[-1] : 0.f;
                        float4 m0 = *(const float4*)(xr);
                        float4 m1 = *(const float4*)(xr + 4);
                        xv[1] = m0.x; xv[2] = m0.y; xv[3] = m0.z; xv[4] = m0.w;
                        xv[5] = m1.x; xv[6] = m1.y; xv[7] = m1.z; xv[8] = m1.w;
                        xv[9] = (w0 < 88) ? xr[8] : 0.f;
                        const float* wrow = wlp + (kd*9 + kh*3) * 4;
                        #pragma unroll
                        for (int kw = 0; kw < 3; ++kw) {
                            float4 w4 = *(const float4*)(wrow + kw*4);
                            #pragma unroll
                            for (int v = 0; v < 8; ++v) {
                                float xx = xv[v + kw];
                                acc[0][v] = fmaf(xx, w4.x, acc[0][v]);
                                acc[1][v] = fmaf(xx, w4.y, acc[1][v]);
                                acc[2][v] = fmaf(xx, w4.z, acc[2][v]);
                                acc[3][v] = fmaf(xx, w4.w, acc[3][v]);
                            }
                        }
                    }
                }
            }
        }
    }

    // mean bias over the 9 (i,j) taps
    float mb[4];
    #pragma unroll
    for (int o = 0; o < 4; ++o) {
        float s = 0.f;
        #pragma unroll
        for (int ij = 0; ij < 9; ++ij) s += bg[ij*4 + o];
        mb[o] = s * (1.0f / 9.0f);
    }

    const float inv9 = 1.0f / 9.0f;
    size_t obase = (size_t)b*10616832 + (size_t)c*442368 + (size_t)t*73728
                 + (size_t)d*9216 + (size_t)h*96 + (size_t)w0;
    #pragma unroll
    for (int o = 0; o < 4; ++o) {
        float4 r0, r1;
        r0.x = acc[o][0]*inv9 + mb[o];
        r0.y = acc[o][1]*inv9 + mb[o];
        r0.z = acc[o][2]*inv9 + mb[o];
        r0.w = acc[o][3]*inv9 + mb[o];
        r1.x = acc[o][4]*inv9 + mb[o];
        r1.y = acc[o][5]*inv9 + mb[o];
        r1.z = acc[o][6]*inv9 + mb[o];
        r1.w = acc[o][7]*inv9 + mb[o];
        float* op = outg + obase + (size_t)o*2654208;
        *(float4*)(op)     = r0;
        *(float4*)(op + 4) = r1;
    }
}

extern "C" void kernel_launch(void* const* d_in, const int* in_sizes, int n_in,
                              void* d_out, int out_size, void* d_ws, size_t ws_size,
                              hipStream_t stream) {
    const float* x = (const float*)d_in[0];
    const float* W = (const float*)d_in[1];
    const float* b = (const float*)d_in[2];
    float* out = (float*)d_out;
    conv5d_kernel<<<2592, BLOCK, 0, stream>>>(x, W, b, out);
}